// Round 4
// baseline (4597.379 us; speedup 1.0000x reference)
//
#include <hip/hip_runtime.h>
#include <hip/hip_bf16.h>
#include <math.h>

// Problem constants
constexpr int  Bb   = 16;
constexpr int  Ll   = 4096;
constexpr int  INd  = 192;
constexpr int  Hd   = 512;
constexpr int  Kn   = 6;
constexpr int  OUTd = 192;
constexpr long Mrows = (long)Bb * Ll;   // 65536

typedef _Float16 f16;
typedef _Float16 f16x8 __attribute__((ext_vector_type(8)));
typedef float    f32x4 __attribute__((ext_vector_type(4)));

__device__ inline void split16(float v, f16& hi, f16& lo) {
    f16 h = (f16)v; hi = h; lo = (f16)(v - (float)h);
}

// ---------------------------------------------------------------------------
// Prep: SSM discretization + weight split-convert (all weights kept N x K)
// ---------------------------------------------------------------------------
__global__ void prep_lam_k(const float* __restrict__ Lre, const float* __restrict__ Lim,
                           const float* __restrict__ lstep,
                           float* lre, float* lim_, float* pre, float* pim,
                           float* cre, float* cim)
{
    int i = blockIdx.x * 256 + threadIdx.x;
    if (i >= Kn * 128) return;
    float lr = Lre[i], li = Lim[i];
    float st = expf(lstep[i]);
    float ar = lr * st, ai = li * st;
    float er = expf(ar);
    float sn, cs; sincosf(ai, &sn, &cs);
    float br = er * cs, bi = er * sn;          // lam_bar
    lre[i] = br; lim_[i] = bi;
    float e2 = expf(64.f * ar);
    float sn2, cs2; sincosf(64.f * ai, &sn2, &cs2);
    pre[i] = e2 * cs2; pim[i] = e2 * sn2;      // lam_bar^64
    float nr = br - 1.f, ni = bi;
    float den = lr * lr + li * li;
    cre[i] = (nr * lr + ni * li) / den;        // (lam_bar-1)/lam
    cim[i] = (ni * lr - nr * li) / den;
}

// Wbu[k]: (256 x 512) rows n<128: Re(B_bar[p=n]), n>=128: Im. split f16.
__global__ void prep_bbar_k(const float* __restrict__ Bre, const float* __restrict__ Bim,
                            const float* __restrict__ cre, const float* __restrict__ cim,
                            f16* __restrict__ Wh, f16* __restrict__ Wl)
{
    int i = blockIdx.x * 256 + threadIdx.x;    // 6*128*512
    int h = i & 511;
    int p = (i >> 9) & 127;
    int k = i >> 16;
    float br = Bre[((size_t)(k * 128 + p)) * 512 + h];
    float bi = Bim[((size_t)(k * 128 + p)) * 512 + h];
    float cr = cre[k * 128 + p], ci = cim[k * 128 + p];
    size_t oR = (size_t)(k * 256 + p) * 512 + h;
    size_t oI = (size_t)(k * 256 + 128 + p) * 512 + h;
    split16(cr * br - ci * bi, Wh[oR], Wl[oR]);
    split16(cr * bi + ci * br, Wh[oI], Wl[oI]);
}

// Wc[k]: (512 x 256): row h, col p<128: 2*C_re[h][p]; col 128+p: -2*C_im[h][p]
__global__ void prep_c_k(const float* __restrict__ Cre, const float* __restrict__ Cim,
                         f16* __restrict__ Wh, f16* __restrict__ Wl)
{
    int i = blockIdx.x * 256 + threadIdx.x;    // 6*512*128
    int p = i & 127;
    int h = (i >> 7) & 511;
    int k = i >> 16;
    float crv = Cre[((size_t)k * 512 + h) * 128 + p];
    float civ = Cim[((size_t)k * 512 + h) * 128 + p];
    size_t o = ((size_t)k * 512 + h) * 256;
    split16( 2.f * crv, Wh[o + p],       Wl[o + p]);
    split16(-2.f * civ, Wh[o + 128 + p], Wl[o + 128 + p]);
}

__global__ void split_w_k(const float* __restrict__ W, f16* __restrict__ Wh,
                          f16* __restrict__ Wl, long n)
{
    long i = (long)blockIdx.x * 256 + threadIdx.x;
    if (i >= n) return;
    split16(W[i], Wh[i], Wl[i]);
}

// activation split: 8 elems/thread, vectorized
__global__ __launch_bounds__(256)
void split_a_k(const float* __restrict__ in, f16* __restrict__ oh,
               f16* __restrict__ ol, long n8)
{
    long i = (long)blockIdx.x * 256 + threadIdx.x;
    if (i >= n8) return;
    const float* p = in + i * 8;
    float v[8];
    *(float4*)&v[0] = *(const float4*)p;
    *(float4*)&v[4] = *(const float4*)(p + 4);
    f16x8 vh, vl;
#pragma unroll
    for (int j = 0; j < 8; ++j) { f16 a, b; split16(v[j], a, b); vh[j] = a; vl[j] = b; }
    *(f16x8*)(oh + i * 8) = vh;
    *(f16x8*)(ol + i * 8) = vl;
}

// ---------------------------------------------------------------------------
// LayerNorm: one wave per row of 512; writes split f16
// ---------------------------------------------------------------------------
__global__ __launch_bounds__(256)
void ln_k(const float* __restrict__ x, f16* __restrict__ oh, f16* __restrict__ ol,
          const float* __restrict__ sc, const float* __restrict__ bi)
{
    const int  lane = threadIdx.x & 63;
    const long row  = (long)blockIdx.x * 4 + (threadIdx.x >> 6);
    const float* p = x + row * 512 + lane * 8;
    float v[8];
    *(float4*)&v[0] = *(const float4*)p;
    *(float4*)&v[4] = *(const float4*)(p + 4);
    float s = 0.f;
#pragma unroll
    for (int j = 0; j < 8; ++j) s += v[j];
#pragma unroll
    for (int m = 1; m < 64; m <<= 1) s += __shfl_xor(s, m, 64);
    const float mu = s * (1.f / 512.f);
    float q = 0.f;
#pragma unroll
    for (int j = 0; j < 8; ++j) { float d = v[j] - mu; q += d * d; }
#pragma unroll
    for (int m = 1; m < 64; m <<= 1) q += __shfl_xor(q, m, 64);
    const float rs = rsqrtf(q * (1.f / 512.f) + 1e-5f);
    float sv[8], bv[8];
    *(float4*)&sv[0] = *(const float4*)(sc + lane * 8);
    *(float4*)&sv[4] = *(const float4*)(sc + lane * 8 + 4);
    *(float4*)&bv[0] = *(const float4*)(bi + lane * 8);
    *(float4*)&bv[4] = *(const float4*)(bi + lane * 8 + 4);
    f16x8 vh, vl;
#pragma unroll
    for (int j = 0; j < 8; ++j) {
        float r = (v[j] - mu) * rs * sv[j] + bv[j];
        f16 a, b; split16(r, a, b); vh[j] = a; vl[j] = b;
    }
    *(f16x8*)(oh + row * 512 + lane * 8) = vh;
    *(f16x8*)(ol + row * 512 + lane * 8) = vl;
}

// ---------------------------------------------------------------------------
// Chunked linear recurrence (complex, fp32 state). Bu: (Mg x 256) fp32.
// ---------------------------------------------------------------------------
__global__ __launch_bounds__(256)
void scan_local_k(const float* __restrict__ Bu, float* __restrict__ fin,
                  const float* __restrict__ lre, const float* __restrict__ lim, int nB)
{
    const int g = blockIdx.x * 256 + threadIdx.x;
    const int p = g & 127;
    const int c = (g >> 7) & 63;
    const int b = g >> 13;
    if (b >= nB) return;
    const float ar = lre[p], ai = lim[p];
    const float* base = Bu + ((long)(b * Ll + c * 64)) * 256 + p;
    float xr = 0.f, xi = 0.f;
#pragma unroll 4
    for (int j = 0; j < 64; ++j) {
        float br  = base[j * 256];
        float bi2 = base[j * 256 + 128];
        float nr = fmaf(ar, xr, fmaf(-ai, xi, br));
        float ni = fmaf(ar, xi, fmaf( ai, xr, bi2));
        xr = nr; xi = ni;
    }
    long o = ((long)(b * 64 + c)) * 256 + p;
    fin[o] = xr; fin[o + 128] = xi;
}

__global__ void scan_carry_k(const float* __restrict__ fin, float* __restrict__ carry,
                             const float* __restrict__ pre, const float* __restrict__ pim,
                             int nB)
{
    const int g = blockIdx.x * 256 + threadIdx.x;
    if (g >= nB * 128) return;
    const int p = g & 127;
    const int b = g >> 7;
    const float pr = pre[p], pi = pim[p];
    float cr = 0.f, ci = 0.f;
    for (int c = 0; c < 64; ++c) {
        long o = ((long)(b * 64 + c)) * 256 + p;
        float fr = fin[o], fi = fin[o + 128];
        carry[o] = cr; carry[o + 128] = ci;
        float nr = fmaf(pr, cr, fmaf(-pi, ci, fr));
        float ni = fmaf(pr, ci, fmaf( pi, cr, fi));
        cr = nr; ci = ni;
    }
}

// replay with carry; writes xs as split f16 (GEMM A operand)
__global__ __launch_bounds__(256)
void scan_final_k(const float* __restrict__ Bu, const float* __restrict__ carry,
                  f16* __restrict__ xh, f16* __restrict__ xl,
                  const float* __restrict__ lre, const float* __restrict__ lim, int nB)
{
    const int g = blockIdx.x * 256 + threadIdx.x;
    const int p = g & 127;
    const int c = (g >> 7) & 63;
    const int b = g >> 13;
    if (b >= nB) return;
    const float ar = lre[p], ai = lim[p];
    long co = ((long)(b * 64 + c)) * 256 + p;
    float xr = carry[co], xi = carry[co + 128];
    const float* base = Bu + ((long)(b * Ll + c * 64)) * 256 + p;
    f16* bh = xh + ((long)(b * Ll + c * 64)) * 256 + p;
    f16* bl = xl + ((long)(b * Ll + c * 64)) * 256 + p;
#pragma unroll 4
    for (int j = 0; j < 64; ++j) {
        float br  = base[j * 256];
        float bi2 = base[j * 256 + 128];
        float nr = fmaf(ar, xr, fmaf(-ai, xi, br));
        float ni = fmaf(ar, xi, fmaf( ai, xr, bi2));
        xr = nr; xi = ni;
        split16(xr, bh[j * 256],       bl[j * 256]);
        split16(xi, bh[j * 256 + 128], bl[j * 256 + 128]);
    }
}

// ---------------------------------------------------------------------------
// Split-fp16 MFMA GEMM, restructured: BM=256, BN in {128,64}, BK=32,
// 256 thr = 4 waves. BN=128: waves 2x2, wave tile 128x64 (FM=8,FN=4).
// BN=64:  waves 4x1, wave tile 64x64  (FM=4,FN=4).
// 2-phase prefetch: global loads for tile t+1 issued before MFMA of tile t.
// A: MxK, B: NxK. 3-term Markidis (Ah*Bh + Ah*Bl + Al*Bh), fp32 acc.
// EPI: 0 store fp32 | 1 +bias store fp32 | 2 gelu(acc+(auxh+auxl)*bias)->split
//    | 3 C += (auxh+auxl)*sigmoid(acc+bias)
// ---------------------------------------------------------------------------
template<int BN, int EPI>
__global__ __launch_bounds__(256)
void mgemm_k(const f16* __restrict__ Ah, const f16* __restrict__ Al,
             const f16* __restrict__ Bh, const f16* __restrict__ Bl,
             float* __restrict__ C, int N, int Kd,
             const float* __restrict__ bias,
             const f16* __restrict__ auxh, const f16* __restrict__ auxl,
             f16* __restrict__ outh, f16* __restrict__ outl)
{
    constexpr int BM = 256, BK = 32, LDA = 40;
    constexpr int FM = (BN == 128) ? 8 : 4;
    constexpr int WM = FM * 16;            // 128 or 64
    constexpr int FN = 4;                  // WN = 64
    __shared__ __align__(16) f16 AsH[BM][LDA], AsL[BM][LDA];
    __shared__ __align__(16) f16 BsH[BN][LDA], BsL[BN][LDA];

    const int tid  = threadIdx.x;
    const int wid  = tid >> 6;
    const int lane = tid & 63;
    const int l15  = lane & 15;
    const int l4   = lane >> 4;
    const int wm   = (BN == 128) ? (wid >> 1) : wid;
    const int wn   = (BN == 128) ? (wid & 1) : 0;

    const long bm = (long)blockIdx.y * BM;
    const int  bn = blockIdx.x * BN;

    f32x4 acc[FM][FN];
#pragma unroll
    for (int i = 0; i < FM; ++i)
#pragma unroll
        for (int j = 0; j < FN; ++j) acc[i][j] = (f32x4){0.f, 0.f, 0.f, 0.f};

    // staging assignment
    const int arow = tid;                                  // A: 1 thread per row, 32k
    const int brow = (BN == 128) ? (tid >> 1) : (tid >> 2);
    const int bko  = (BN == 128) ? ((tid & 1) * 16) : ((tid & 3) * 8);
    constexpr int NBL = (BN == 128) ? 2 : 1;               // b f16x8 loads per array

    f16x8 rah[4], ral[4], rbh[2], rbl[2];

    auto LOADT = [&](int k0) {
        const long aoff = (bm + arow) * (long)Kd + k0;
#pragma unroll
        for (int q = 0; q < 4; ++q) {
            rah[q] = *(const f16x8*)(Ah + aoff + q * 8);
            ral[q] = *(const f16x8*)(Al + aoff + q * 8);
        }
        const long boff = (long)(bn + brow) * Kd + k0 + bko;
#pragma unroll
        for (int q = 0; q < NBL; ++q) {
            rbh[q] = *(const f16x8*)(Bh + boff + q * 8);
            rbl[q] = *(const f16x8*)(Bl + boff + q * 8);
        }
    };

    LOADT(0);
    for (int k0 = 0; k0 < Kd; k0 += BK) {
        __syncthreads();                         // prev-tile consumers done
#pragma unroll
        for (int q = 0; q < 4; ++q) {
            *(f16x8*)&AsH[arow][q * 8] = rah[q];
            *(f16x8*)&AsL[arow][q * 8] = ral[q];
        }
#pragma unroll
        for (int q = 0; q < NBL; ++q) {
            *(f16x8*)&BsH[brow][bko + q * 8] = rbh[q];
            *(f16x8*)&BsL[brow][bko + q * 8] = rbl[q];
        }
        __syncthreads();
        if (k0 + BK < Kd) LOADT(k0 + BK);        // prefetch next tile (in flight over MFMA)

        f16x8 bfh[FN], bfl[FN];
#pragma unroll
        for (int j = 0; j < FN; ++j) {
            bfh[j] = *(const f16x8*)&BsH[wn * 64 + j * 16 + l15][l4 * 8];
            bfl[j] = *(const f16x8*)&BsL[wn * 64 + j * 16 + l15][l4 * 8];
        }
#pragma unroll
        for (int i = 0; i < FM; ++i) {
            f16x8 ah = *(const f16x8*)&AsH[wm * WM + i * 16 + l15][l4 * 8];
            f16x8 al = *(const f16x8*)&AsL[wm * WM + i * 16 + l15][l4 * 8];
#pragma unroll
            for (int j = 0; j < FN; ++j) {
                acc[i][j] = __builtin_amdgcn_mfma_f32_16x16x32_f16(ah, bfh[j], acc[i][j], 0, 0, 0);
                acc[i][j] = __builtin_amdgcn_mfma_f32_16x16x32_f16(ah, bfl[j], acc[i][j], 0, 0, 0);
                acc[i][j] = __builtin_amdgcn_mfma_f32_16x16x32_f16(al, bfh[j], acc[i][j], 0, 0, 0);
            }
        }
    }

#pragma unroll
    for (int i = 0; i < FM; ++i)
#pragma unroll
        for (int j = 0; j < FN; ++j) {
            const int n = bn + wn * 64 + j * 16 + l15;
            float bv = 0.f;
            if constexpr (EPI != 0) bv = bias[n];
#pragma unroll
            for (int r = 0; r < 4; ++r) {
                const long m = bm + wm * WM + i * 16 + l4 * 4 + r;
                const long off = m * N + n;
                float v = acc[i][j][r];
                if constexpr (EPI == 0) {
                    C[off] = v;
                } else if constexpr (EPI == 1) {
                    C[off] = v + bv;
                } else if constexpr (EPI == 2) {
                    float u = (float)auxh[off] + (float)auxl[off];
                    float y = v + u * bv;
                    float t = tanhf(0.7978845608028654f * (y + 0.044715f * y * y * y));
                    float g = 0.5f * y * (1.f + t);
                    split16(g, outh[off], outl[off]);
                } else {  // EPI == 3
                    float gfull = (float)auxh[off] + (float)auxl[off];
                    float z = v + bv;
                    C[off] += gfull / (1.f + expf(-z));
                }
            }
        }
}

// ---------------------------------------------------------------------------
// Launch (workspace-adaptive grouping over the 16 independent sequences)
// ---------------------------------------------------------------------------
extern "C" void kernel_launch(void* const* d_in, const int* in_sizes, int n_in,
                              void* d_out, int out_size, void* d_ws, size_t ws_size,
                              hipStream_t stream)
{
    const float* x        = (const float*)d_in[0];
    const float* W_enc    = (const float*)d_in[1];
    const float* b_enc    = (const float*)d_in[2];
    const float* ln_scale = (const float*)d_in[3];
    const float* ln_bias  = (const float*)d_in[4];
    const float* Lre      = (const float*)d_in[5];
    const float* Lim      = (const float*)d_in[6];
    const float* B_re     = (const float*)d_in[7];
    const float* B_im     = (const float*)d_in[8];
    const float* C_re     = (const float*)d_in[9];
    const float* C_im     = (const float*)d_in[10];
    const float* Dv       = (const float*)d_in[11];
    const float* log_step = (const float*)d_in[12];
    const float* W_glu    = (const float*)d_in[13];
    const float* b_glu    = (const float*)d_in[14];
    const float* W_dec    = (const float*)d_in[15];
    const float* b_dec    = (const float*)d_in[16];
    float* out = (float*)d_out;

    char* w = (char*)d_ws;
    auto alloc = [&](size_t nbytes) { char* p = w; w += (nbytes + 255) & ~255ull; return p; };

    float* lam_re = (float*)alloc(768 * 4);
    float* lam_im = (float*)alloc(768 * 4);
    float* pow_re = (float*)alloc(768 * 4);
    float* pow_im = (float*)alloc(768 * 4);
    float* coef_re= (float*)alloc(768 * 4);
    float* coef_im= (float*)alloc(768 * 4);
    float* fin    = (float*)alloc((size_t)Bb * 64 * 256 * 4);
    float* carry  = (float*)alloc((size_t)Bb * 64 * 256 * 4);
    f16* WencH = (f16*)alloc((size_t)Hd * INd * 2);
    f16* WencL = (f16*)alloc((size_t)Hd * INd * 2);
    f16* WbuH  = (f16*)alloc((size_t)Kn * 256 * Hd * 2);
    f16* WbuL  = (f16*)alloc((size_t)Kn * 256 * Hd * 2);
    f16* WcH   = (f16*)alloc((size_t)Kn * Hd * 256 * 2);
    f16* WcL   = (f16*)alloc((size_t)Kn * Hd * 256 * 2);
    f16* WgluH = (f16*)alloc((size_t)Kn * Hd * Hd * 2);
    f16* WgluL = (f16*)alloc((size_t)Kn * Hd * Hd * 2);
    f16* WdecH = (f16*)alloc((size_t)OUTd * Hd * 2);
    f16* WdecL = (f16*)alloc((size_t)OUTd * Hd * 2);
    const size_t fixed_bytes = (size_t)(w - (char*)d_ws);

    // per-row activation bytes: h(2048) + uhl(2048) + Bu(1024) + xshl(1024) + xhl(768)
    int G = 1;
    for (; G < 16; G *= 2) {
        size_t Mg = Mrows / G;
        if (fixed_bytes + Mg * 6912ull <= ws_size) break;
    }
    const long Bg = Bb / G;
    const long Mg = Bg * Ll;

    float* h   = (float*)alloc((size_t)Mg * Hd * 4);
    f16*   uh  = (f16*)alloc((size_t)Mg * Hd * 2);
    f16*   ul  = (f16*)alloc((size_t)Mg * Hd * 2);
    float* Bu  = (float*)alloc((size_t)Mg * 256 * 4);
    f16*   xsh = (f16*)alloc((size_t)Mg * 256 * 2);
    f16*   xsl = (f16*)alloc((size_t)Mg * 256 * 2);
    f16*   xh  = (f16*)alloc((size_t)Mg * INd * 2);
    f16*   xl  = (f16*)alloc((size_t)Mg * INd * 2);

    // --- prep ---
    prep_lam_k <<<3,    256, 0, stream>>>(Lre, Lim, log_step, lam_re, lam_im,
                                          pow_re, pow_im, coef_re, coef_im);
    prep_bbar_k<<<1536, 256, 0, stream>>>(B_re, B_im, coef_re, coef_im, WbuH, WbuL);
    prep_c_k   <<<1536, 256, 0, stream>>>(C_re, C_im, WcH, WcL);
    split_w_k  <<<6144, 256, 0, stream>>>(W_glu, WgluH, WgluL, (long)Kn * Hd * Hd);
    split_w_k  <<<384,  256, 0, stream>>>(W_enc, WencH, WencL, (long)Hd * INd);
    split_w_k  <<<384,  256, 0, stream>>>(W_dec, WdecH, WdecL, (long)OUTd * Hd);

    const dim3 blk(256);
    const int gy = (int)(Mg / 256);
    for (int g0 = 0; g0 < G; ++g0) {
        const float* xg   = x   + (size_t)g0 * Mg * INd;
        float*       outg = out + (size_t)g0 * Mg * OUTd;

        // split x, then encoder: h = x @ Wenc^T + b_enc
        split_a_k<<<(int)(Mg * INd / 2048), 256, 0, stream>>>(xg, xh, xl, Mg * INd / 8);
        mgemm_k<128, 1><<<dim3(4, gy), blk, 0, stream>>>(
            xh, xl, WencH, WencL, h, 512, INd, b_enc, nullptr, nullptr, nullptr, nullptr);

        for (int k = 0; k < Kn; ++k) {
            ln_k<<<(int)(Mg / 4), 256, 0, stream>>>(h, uh, ul,
                                                    ln_scale + k * 512, ln_bias + k * 512);
            // Bu = u @ Wbu[k]^T (M x 256, K=512)
            mgemm_k<128, 0><<<dim3(2, gy), blk, 0, stream>>>(
                uh, ul, WbuH + (size_t)k * 256 * Hd, WbuL + (size_t)k * 256 * Hd,
                Bu, 256, 512, nullptr, nullptr, nullptr, nullptr, nullptr);
            scan_local_k<<<(int)(Bg * 32), 256, 0, stream>>>(
                Bu, fin, lam_re + k * 128, lam_im + k * 128, (int)Bg);
            scan_carry_k<<<(int)((Bg * 128 + 255) / 256), 256, 0, stream>>>(
                fin, carry, pow_re + k * 128, pow_im + k * 128, (int)Bg);
            scan_final_k<<<(int)(Bg * 32), 256, 0, stream>>>(
                Bu, carry, xsh, xsl, lam_re + k * 128, lam_im + k * 128, (int)Bg);
            // g = gelu(xs @ Wc[k]^T + u*D), written split in place over u
            mgemm_k<128, 2><<<dim3(4, gy), blk, 0, stream>>>(
                xsh, xsl, WcH + (size_t)k * Hd * 256, WcL + (size_t)k * Hd * 256,
                nullptr, 512, 256, Dv + k * 512, uh, ul, uh, ul);
            // h += g * sigmoid(g @ Wglu[k]^T + b_glu)
            mgemm_k<128, 3><<<dim3(4, gy), blk, 0, stream>>>(
                uh, ul, WgluH + (size_t)k * Hd * Hd, WgluL + (size_t)k * Hd * Hd,
                h, 512, 512, b_glu + k * 512, uh, ul, nullptr, nullptr);
        }
        // decoder: split h (reuse uh/ul), out = h @ Wdec^T + b_dec (N=192, BN=64)
        split_a_k<<<(int)(Mg * Hd / 2048), 256, 0, stream>>>(h, uh, ul, Mg * Hd / 8);
        mgemm_k<64, 1><<<dim3(3, gy), blk, 0, stream>>>(
            uh, ul, WdecH, WdecL, outg, 192, 512, b_dec, nullptr, nullptr, nullptr, nullptr);
    }
}

// Round 5
// 2471.226 us; speedup vs baseline: 1.8604x; 1.8604x over previous
//
#include <hip/hip_runtime.h>
#include <math.h>

// Problem constants
constexpr int  Bb   = 16;
constexpr int  Ll   = 4096;
constexpr int  INd  = 192;
constexpr int  Hd   = 512;
constexpr int  Kn   = 6;
constexpr int  OUTd = 192;
constexpr long Mrows = (long)Bb * Ll;   // 65536

typedef _Float16 f16;
typedef _Float16 f16x8 __attribute__((ext_vector_type(8)));
typedef float    f32x4 __attribute__((ext_vector_type(4)));

// ---------------------------------------------------------------------------
// Prep: SSM discretization + weight convert to fp16 (all weights N x K)
// ---------------------------------------------------------------------------
__global__ void prep_lam_k(const float* __restrict__ Lre, const float* __restrict__ Lim,
                           const float* __restrict__ lstep,
                           float* lre, float* lim_, float* pre, float* pim,
                           float* cre, float* cim)
{
    int i = blockIdx.x * 256 + threadIdx.x;
    if (i >= Kn * 128) return;
    float lr = Lre[i], li = Lim[i];
    float st = expf(lstep[i]);
    float ar = lr * st, ai = li * st;
    float er = expf(ar);
    float sn, cs; sincosf(ai, &sn, &cs);
    float br = er * cs, bi = er * sn;          // lam_bar
    lre[i] = br; lim_[i] = bi;
    float e2 = expf(64.f * ar);
    float sn2, cs2; sincosf(64.f * ai, &sn2, &cs2);
    pre[i] = e2 * cs2; pim[i] = e2 * sn2;      // lam_bar^64
    float nr = br - 1.f, ni = bi;
    float den = lr * lr + li * li;
    cre[i] = (nr * lr + ni * li) / den;        // (lam_bar-1)/lam
    cim[i] = (ni * lr - nr * li) / den;
}

// Wbu[k]: (256 x 512) rows n<128: Re(B_bar[p=n]), n>=128: Im.  fp16.
__global__ void prep_bbar_k(const float* __restrict__ Bre, const float* __restrict__ Bim,
                            const float* __restrict__ cre, const float* __restrict__ cim,
                            f16* __restrict__ Wh)
{
    int i = blockIdx.x * 256 + threadIdx.x;    // 6*128*512
    int h = i & 511;
    int p = (i >> 9) & 127;
    int k = i >> 16;
    float br = Bre[((size_t)(k * 128 + p)) * 512 + h];
    float bi = Bim[((size_t)(k * 128 + p)) * 512 + h];
    float cr = cre[k * 128 + p], ci = cim[k * 128 + p];
    Wh[(size_t)(k * 256 + p) * 512 + h]       = (f16)(cr * br - ci * bi);
    Wh[(size_t)(k * 256 + 128 + p) * 512 + h] = (f16)(cr * bi + ci * br);
}

// Wc[k]: (512 x 256): row h, col p<128: 2*C_re[h][p]; col 128+p: -2*C_im[h][p]
__global__ void prep_c_k(const float* __restrict__ Cre, const float* __restrict__ Cim,
                         f16* __restrict__ Wh)
{
    int i = blockIdx.x * 256 + threadIdx.x;    // 6*512*128
    int p = i & 127;
    int h = (i >> 7) & 511;
    int k = i >> 16;
    float crv = Cre[((size_t)k * 512 + h) * 128 + p];
    float civ = Cim[((size_t)k * 512 + h) * 128 + p];
    size_t o = ((size_t)k * 512 + h) * 256;
    Wh[o + p]       = (f16)( 2.f * crv);
    Wh[o + 128 + p] = (f16)(-2.f * civ);
}

__global__ void cvt_w_k(const float* __restrict__ W, f16* __restrict__ Wh, long n)
{
    long i = (long)blockIdx.x * 256 + threadIdx.x;
    if (i >= n) return;
    Wh[i] = (f16)W[i];
}

// fp32 -> fp16 convert, 8 elems/thread, vectorized
__global__ __launch_bounds__(256)
void cvt_a_k(const float* __restrict__ in, f16* __restrict__ oh, long n8)
{
    long i = (long)blockIdx.x * 256 + threadIdx.x;
    if (i >= n8) return;
    const float* p = in + i * 8;
    float v[8];
    *(float4*)&v[0] = *(const float4*)p;
    *(float4*)&v[4] = *(const float4*)(p + 4);
    f16x8 vh;
#pragma unroll
    for (int j = 0; j < 8; ++j) vh[j] = (f16)v[j];
    *(f16x8*)(oh + i * 8) = vh;
}

// ---------------------------------------------------------------------------
// LayerNorm: one wave per row of 512; writes fp16
// ---------------------------------------------------------------------------
__global__ __launch_bounds__(256)
void ln_k(const float* __restrict__ x, f16* __restrict__ oh,
          const float* __restrict__ sc, const float* __restrict__ bi)
{
    const int  lane = threadIdx.x & 63;
    const long row  = (long)blockIdx.x * 4 + (threadIdx.x >> 6);
    const float* p = x + row * 512 + lane * 8;
    float v[8];
    *(float4*)&v[0] = *(const float4*)p;
    *(float4*)&v[4] = *(const float4*)(p + 4);
    float s = 0.f;
#pragma unroll
    for (int j = 0; j < 8; ++j) s += v[j];
#pragma unroll
    for (int m = 1; m < 64; m <<= 1) s += __shfl_xor(s, m, 64);
    const float mu = s * (1.f / 512.f);
    float q = 0.f;
#pragma unroll
    for (int j = 0; j < 8; ++j) { float d = v[j] - mu; q += d * d; }
#pragma unroll
    for (int m = 1; m < 64; m <<= 1) q += __shfl_xor(q, m, 64);
    const float rs = rsqrtf(q * (1.f / 512.f) + 1e-5f);
    float sv[8], bv[8];
    *(float4*)&sv[0] = *(const float4*)(sc + lane * 8);
    *(float4*)&sv[4] = *(const float4*)(sc + lane * 8 + 4);
    *(float4*)&bv[0] = *(const float4*)(bi + lane * 8);
    *(float4*)&bv[4] = *(const float4*)(bi + lane * 8 + 4);
    f16x8 vh;
#pragma unroll
    for (int j = 0; j < 8; ++j)
        vh[j] = (f16)((v[j] - mu) * rs * sv[j] + bv[j]);
    *(f16x8*)(oh + row * 512 + lane * 8) = vh;
}

// ---------------------------------------------------------------------------
// Chunked linear recurrence (complex, fp32 state). Bu: (Mg x 256) fp32.
// ---------------------------------------------------------------------------
__global__ __launch_bounds__(256)
void scan_local_k(const float* __restrict__ Bu, float* __restrict__ fin,
                  const float* __restrict__ lre, const float* __restrict__ lim, int nB)
{
    const int g = blockIdx.x * 256 + threadIdx.x;
    const int p = g & 127;
    const int c = (g >> 7) & 63;
    const int b = g >> 13;
    if (b >= nB) return;
    const float ar = lre[p], ai = lim[p];
    const float* base = Bu + ((long)(b * Ll + c * 64)) * 256 + p;
    float xr = 0.f, xi = 0.f;
#pragma unroll 4
    for (int j = 0; j < 64; ++j) {
        float br  = base[j * 256];
        float bi2 = base[j * 256 + 128];
        float nr = fmaf(ar, xr, fmaf(-ai, xi, br));
        float ni = fmaf(ar, xi, fmaf( ai, xr, bi2));
        xr = nr; xi = ni;
    }
    long o = ((long)(b * 64 + c)) * 256 + p;
    fin[o] = xr; fin[o + 128] = xi;
}

__global__ void scan_carry_k(const float* __restrict__ fin, float* __restrict__ carry,
                             const float* __restrict__ pre, const float* __restrict__ pim,
                             int nB)
{
    const int g = blockIdx.x * 256 + threadIdx.x;
    if (g >= nB * 128) return;
    const int p = g & 127;
    const int b = g >> 7;
    const float pr = pre[p], pi = pim[p];
    float cr = 0.f, ci = 0.f;
    for (int c = 0; c < 64; ++c) {
        long o = ((long)(b * 64 + c)) * 256 + p;
        float fr = fin[o], fi = fin[o + 128];
        carry[o] = cr; carry[o + 128] = ci;
        float nr = fmaf(pr, cr, fmaf(-pi, ci, fr));
        float ni = fmaf(pr, ci, fmaf( pi, cr, fi));
        cr = nr; ci = ni;
    }
}

// replay with carry; writes xs as fp16 (GEMM A operand)
__global__ __launch_bounds__(256)
void scan_final_k(const float* __restrict__ Bu, const float* __restrict__ carry,
                  f16* __restrict__ xh,
                  const float* __restrict__ lre, const float* __restrict__ lim, int nB)
{
    const int g = blockIdx.x * 256 + threadIdx.x;
    const int p = g & 127;
    const int c = (g >> 7) & 63;
    const int b = g >> 13;
    if (b >= nB) return;
    const float ar = lre[p], ai = lim[p];
    long co = ((long)(b * 64 + c)) * 256 + p;
    float xr = carry[co], xi = carry[co + 128];
    const float* base = Bu + ((long)(b * Ll + c * 64)) * 256 + p;
    f16* bh = xh + ((long)(b * Ll + c * 64)) * 256 + p;
#pragma unroll 4
    for (int j = 0; j < 64; ++j) {
        float br  = base[j * 256];
        float bi2 = base[j * 256 + 128];
        float nr = fmaf(ar, xr, fmaf(-ai, xi, br));
        float ni = fmaf(ar, xi, fmaf( ai, xr, bi2));
        xr = nr; xi = ni;
        bh[j * 256]       = (f16)xr;
        bh[j * 256 + 128] = (f16)xi;
    }
}

// ---------------------------------------------------------------------------
// fp16 MFMA GEMM (single term, fp32 acc): C(MxN) = A(MxK) @ Bw(NxK)^T.
// BM=128, BN in {128,64}, BK=32, 256 thr = 4 waves.
// BN=128: waves 2x2, wave tile 64x64 (FM=4,FN=4).
// BN=64:  waves 4x1, wave tile 32x64 (FM=2,FN=4).
// Prefetch: global loads for tile t+1 issued before MFMA of tile t.
// EPI: 0 store fp32 | 1 +bias store fp32 | 2 gelu(acc + aux*bias)->fp16
//    | 3 C += aux * sigmoid(acc + bias)
// ---------------------------------------------------------------------------
template<int BN, int EPI>
__global__ __launch_bounds__(256)
void mgemm_k(const f16* __restrict__ A, const f16* __restrict__ Bw,
             float* __restrict__ C, int N, int Kd,
             const float* __restrict__ bias,
             const f16* __restrict__ aux, f16* __restrict__ outq)
{
    constexpr int BM = 128, BK = 32, LDA = 40;
    constexpr int FM = (BN == 128) ? 4 : 2;
    constexpr int WM = FM * 16;            // 64 or 32
    constexpr int FN = 4;                  // WN = 64
    __shared__ __align__(16) f16 As[BM][LDA];
    __shared__ __align__(16) f16 Bs[BN][LDA];

    const int tid  = threadIdx.x;
    const int wid  = tid >> 6;
    const int lane = tid & 63;
    const int l15  = lane & 15;
    const int l4   = lane >> 4;
    const int wm   = (BN == 128) ? (wid >> 1) : wid;
    const int wn   = (BN == 128) ? (wid & 1) : 0;

    const long bm = (long)blockIdx.y * BM;
    const int  bn = blockIdx.x * BN;

    f32x4 acc[FM][FN];
#pragma unroll
    for (int i = 0; i < FM; ++i)
#pragma unroll
        for (int j = 0; j < FN; ++j) acc[i][j] = (f32x4){0.f, 0.f, 0.f, 0.f};

    // staging assignment
    const int arow = tid >> 1;
    const int akc  = (tid & 1) * 16;
    const int brow = (BN == 128) ? (tid >> 1) : (tid >> 2);
    const int bko  = (BN == 128) ? ((tid & 1) * 16) : ((tid & 3) * 8);
    constexpr int NBL = (BN == 128) ? 2 : 1;

    f16x8 ra[2], rb[2];
    auto LOADT = [&](int k0) {
        const long aoff = (bm + arow) * (long)Kd + k0 + akc;
        ra[0] = *(const f16x8*)(A + aoff);
        ra[1] = *(const f16x8*)(A + aoff + 8);
        const long boff = (long)(bn + brow) * Kd + k0 + bko;
        rb[0] = *(const f16x8*)(Bw + boff);
        if constexpr (NBL == 2) rb[1] = *(const f16x8*)(Bw + boff + 8);
    };

    LOADT(0);
    for (int k0 = 0; k0 < Kd; k0 += BK) {
        __syncthreads();                     // prev-tile consumers done
        *(f16x8*)&As[arow][akc]     = ra[0];
        *(f16x8*)&As[arow][akc + 8] = ra[1];
        *(f16x8*)&Bs[brow][bko] = rb[0];
        if constexpr (NBL == 2) *(f16x8*)&Bs[brow][bko + 8] = rb[1];
        __syncthreads();
        if (k0 + BK < Kd) LOADT(k0 + BK);    // prefetch next tile over MFMA phase

        f16x8 bf[FN];
#pragma unroll
        for (int j = 0; j < FN; ++j)
            bf[j] = *(const f16x8*)&Bs[wn * 64 + j * 16 + l15][l4 * 8];
#pragma unroll
        for (int i = 0; i < FM; ++i) {
            f16x8 af = *(const f16x8*)&As[wm * WM + i * 16 + l15][l4 * 8];
#pragma unroll
            for (int j = 0; j < FN; ++j)
                acc[i][j] = __builtin_amdgcn_mfma_f32_16x16x32_f16(af, bf[j], acc[i][j], 0, 0, 0);
        }
    }

#pragma unroll
    for (int i = 0; i < FM; ++i)
#pragma unroll
        for (int j = 0; j < FN; ++j) {
            const int n = bn + wn * 64 + j * 16 + l15;
            float bv = 0.f;
            if constexpr (EPI != 0) bv = bias[n];
#pragma unroll
            for (int r = 0; r < 4; ++r) {
                const long m = bm + wm * WM + i * 16 + l4 * 4 + r;
                const long off = m * N + n;
                float v = acc[i][j][r];
                if constexpr (EPI == 0) {
                    C[off] = v;
                } else if constexpr (EPI == 1) {
                    C[off] = v + bv;
                } else if constexpr (EPI == 2) {
                    float y = v + (float)aux[off] * bv;
                    float t = tanhf(0.7978845608028654f * (y + 0.044715f * y * y * y));
                    outq[off] = (f16)(0.5f * y * (1.f + t));
                } else {  // EPI == 3
                    float z = v + bv;
                    C[off] += (float)aux[off] / (1.f + expf(-z));
                }
            }
        }
}

// ---------------------------------------------------------------------------
// Launch (workspace-adaptive grouping over the 16 independent sequences)
// ---------------------------------------------------------------------------
extern "C" void kernel_launch(void* const* d_in, const int* in_sizes, int n_in,
                              void* d_out, int out_size, void* d_ws, size_t ws_size,
                              hipStream_t stream)
{
    const float* x        = (const float*)d_in[0];
    const float* W_enc    = (const float*)d_in[1];
    const float* b_enc    = (const float*)d_in[2];
    const float* ln_scale = (const float*)d_in[3];
    const float* ln_bias  = (const float*)d_in[4];
    const float* Lre      = (const float*)d_in[5];
    const float* Lim      = (const float*)d_in[6];
    const float* B_re     = (const float*)d_in[7];
    const float* B_im     = (const float*)d_in[8];
    const float* C_re     = (const float*)d_in[9];
    const float* C_im     = (const float*)d_in[10];
    const float* Dv       = (const float*)d_in[11];
    const float* log_step = (const float*)d_in[12];
    const float* W_glu    = (const float*)d_in[13];
    const float* b_glu    = (const float*)d_in[14];
    const float* W_dec    = (const float*)d_in[15];
    const float* b_dec    = (const float*)d_in[16];
    float* out = (float*)d_out;

    char* w = (char*)d_ws;
    auto alloc = [&](size_t nbytes) { char* p = w; w += (nbytes + 255) & ~255ull; return p; };

    float* lam_re = (float*)alloc(768 * 4);
    float* lam_im = (float*)alloc(768 * 4);
    float* pow_re = (float*)alloc(768 * 4);
    float* pow_im = (float*)alloc(768 * 4);
    float* coef_re= (float*)alloc(768 * 4);
    float* coef_im= (float*)alloc(768 * 4);
    float* fin    = (float*)alloc((size_t)Bb * 64 * 256 * 4);
    float* carry  = (float*)alloc((size_t)Bb * 64 * 256 * 4);
    f16* WencH = (f16*)alloc((size_t)Hd * INd * 2);
    f16* WbuH  = (f16*)alloc((size_t)Kn * 256 * Hd * 2);
    f16* WcH   = (f16*)alloc((size_t)Kn * Hd * 256 * 2);
    f16* WgluH = (f16*)alloc((size_t)Kn * Hd * Hd * 2);
    f16* WdecH = (f16*)alloc((size_t)OUTd * Hd * 2);
    const size_t fixed_bytes = (size_t)(w - (char*)d_ws);

    // per-row bytes: h(2048) + uh(1024) + Bu(1024) + xs(512) + xh(384) = 4992
    int G = 1;
    for (; G < 16; G *= 2) {
        size_t Mg = Mrows / G;
        if (fixed_bytes + Mg * 4992ull <= ws_size) break;
    }
    const long Bg = Bb / G;
    const long Mg = Bg * Ll;

    float* h   = (float*)alloc((size_t)Mg * Hd * 4);
    f16*   uh  = (f16*)alloc((size_t)Mg * Hd * 2);     // LN out; g; fp16(h) for decoder
    float* Bu  = (float*)alloc((size_t)Mg * 256 * 4);
    f16*   xsh = (f16*)alloc((size_t)Mg * 256 * 2);
    f16*   xh  = (f16*)alloc((size_t)Mg * INd * 2);

    // --- prep ---
    prep_lam_k <<<3,    256, 0, stream>>>(Lre, Lim, log_step, lam_re, lam_im,
                                          pow_re, pow_im, coef_re, coef_im);
    prep_bbar_k<<<1536, 256, 0, stream>>>(B_re, B_im, coef_re, coef_im, WbuH);
    prep_c_k   <<<1536, 256, 0, stream>>>(C_re, C_im, WcH);
    cvt_w_k    <<<6144, 256, 0, stream>>>(W_glu, WgluH, (long)Kn * Hd * Hd);
    cvt_w_k    <<<384,  256, 0, stream>>>(W_enc, WencH, (long)Hd * INd);
    cvt_w_k    <<<384,  256, 0, stream>>>(W_dec, WdecH, (long)OUTd * Hd);

    const dim3 blk(256);
    const int gy = (int)(Mg / 128);
    for (int g0 = 0; g0 < G; ++g0) {
        const float* xg   = x   + (size_t)g0 * Mg * INd;
        float*       outg = out + (size_t)g0 * Mg * OUTd;

        // convert x, then encoder: h = x @ Wenc^T + b_enc
        cvt_a_k<<<(int)(Mg * INd / 2048), 256, 0, stream>>>(xg, xh, Mg * INd / 8);
        mgemm_k<128, 1><<<dim3(4, gy), blk, 0, stream>>>(
            xh, WencH, h, 512, INd, b_enc, nullptr, nullptr);

        for (int k = 0; k < Kn; ++k) {
            ln_k<<<(int)(Mg / 4), 256, 0, stream>>>(h, uh,
                                                    ln_scale + k * 512, ln_bias + k * 512);
            // Bu = u @ Wbu[k]^T (M x 256, K=512)
            mgemm_k<128, 0><<<dim3(2, gy), blk, 0, stream>>>(
                uh, WbuH + (size_t)k * 256 * Hd, Bu, 256, 512, nullptr, nullptr, nullptr);
            scan_local_k<<<(int)(Bg * 32), 256, 0, stream>>>(
                Bu, fin, lam_re + k * 128, lam_im + k * 128, (int)Bg);
            scan_carry_k<<<(int)((Bg * 128 + 255) / 256), 256, 0, stream>>>(
                fin, carry, pow_re + k * 128, pow_im + k * 128, (int)Bg);
            scan_final_k<<<(int)(Bg * 32), 256, 0, stream>>>(
                Bu, carry, xsh, lam_re + k * 128, lam_im + k * 128, (int)Bg);
            // g = gelu(xs @ Wc[k]^T + u*D), fp16, in place over u
            mgemm_k<128, 2><<<dim3(4, gy), blk, 0, stream>>>(
                xsh, WcH + (size_t)k * Hd * 256, nullptr, 512, 256,
                Dv + k * 512, uh, uh);
            // h += g * sigmoid(g @ Wglu[k]^T + b_glu)
            mgemm_k<128, 3><<<dim3(4, gy), blk, 0, stream>>>(
                uh, WgluH + (size_t)k * Hd * Hd, h, 512, 512,
                b_glu + k * 512, uh, nullptr);
        }
        // decoder: convert h to fp16 (reuse uh), out = h @ Wdec^T + b_dec
        cvt_a_k<<<(int)(Mg * Hd / 2048), 256, 0, stream>>>(h, uh, Mg * Hd / 8);
        mgemm_k<64, 1><<<dim3(3, gy), blk, 0, stream>>>(
            uh, WdecH, outg, 192, 512, b_dec, nullptr, nullptr);
    }
}

// Round 6
// 1999.640 us; speedup vs baseline: 2.2991x; 1.2358x over previous
//
#include <hip/hip_runtime.h>
#include <math.h>

// Problem constants
constexpr int  Bb   = 16;
constexpr int  Ll   = 4096;
constexpr int  INd  = 192;
constexpr int  Hd   = 512;
constexpr int  Kn   = 6;
constexpr int  OUTd = 192;
constexpr long Mrows = (long)Bb * Ll;   // 65536

typedef _Float16 f16;
typedef _Float16 f16x8 __attribute__((ext_vector_type(8)));
typedef _Float16 f16x4 __attribute__((ext_vector_type(4)));
typedef float    f32x4 __attribute__((ext_vector_type(4)));

// ---------------------------------------------------------------------------
// Prep: SSM discretization + weight convert to fp16 (all weights N x K)
// ---------------------------------------------------------------------------
__global__ void prep_lam_k(const float* __restrict__ Lre, const float* __restrict__ Lim,
                           const float* __restrict__ lstep,
                           float* lre, float* lim_, float* pre, float* pim,
                           float* cre, float* cim)
{
    int i = blockIdx.x * 256 + threadIdx.x;
    if (i >= Kn * 128) return;
    float lr = Lre[i], li = Lim[i];
    float st = expf(lstep[i]);
    float ar = lr * st, ai = li * st;
    float er = expf(ar);
    float sn, cs; sincosf(ai, &sn, &cs);
    float br = er * cs, bi = er * sn;          // lam_bar
    lre[i] = br; lim_[i] = bi;
    float e2 = expf(64.f * ar);
    float sn2, cs2; sincosf(64.f * ai, &sn2, &cs2);
    pre[i] = e2 * cs2; pim[i] = e2 * sn2;      // lam_bar^64
    float nr = br - 1.f, ni = bi;
    float den = lr * lr + li * li;
    cre[i] = (nr * lr + ni * li) / den;        // (lam_bar-1)/lam
    cim[i] = (ni * lr - nr * li) / den;
}

// Wbu[k]: (256 x 512) rows n<128: Re(B_bar[p=n]), n>=128: Im.  fp16.
__global__ void prep_bbar_k(const float* __restrict__ Bre, const float* __restrict__ Bim,
                            const float* __restrict__ cre, const float* __restrict__ cim,
                            f16* __restrict__ Wh)
{
    int i = blockIdx.x * 256 + threadIdx.x;    // 6*128*512
    int h = i & 511;
    int p = (i >> 9) & 127;
    int k = i >> 16;
    float br = Bre[((size_t)(k * 128 + p)) * 512 + h];
    float bi = Bim[((size_t)(k * 128 + p)) * 512 + h];
    float cr = cre[k * 128 + p], ci = cim[k * 128 + p];
    Wh[(size_t)(k * 256 + p) * 512 + h]       = (f16)(cr * br - ci * bi);
    Wh[(size_t)(k * 256 + 128 + p) * 512 + h] = (f16)(cr * bi + ci * br);
}

// Wc[k]: (512 x 256): row h, col p<128: 2*C_re[h][p]; col 128+p: -2*C_im[h][p]
__global__ void prep_c_k(const float* __restrict__ Cre, const float* __restrict__ Cim,
                         f16* __restrict__ Wh)
{
    int i = blockIdx.x * 256 + threadIdx.x;    // 6*512*128
    int p = i & 127;
    int h = (i >> 7) & 511;
    int k = i >> 16;
    float crv = Cre[((size_t)k * 512 + h) * 128 + p];
    float civ = Cim[((size_t)k * 512 + h) * 128 + p];
    size_t o = ((size_t)k * 512 + h) * 256;
    Wh[o + p]       = (f16)( 2.f * crv);
    Wh[o + 128 + p] = (f16)(-2.f * civ);
}

__global__ void cvt_w_k(const float* __restrict__ W, f16* __restrict__ Wh, long n)
{
    long i = (long)blockIdx.x * 256 + threadIdx.x;
    if (i >= n) return;
    Wh[i] = (f16)W[i];
}

// ---------------------------------------------------------------------------
// LayerNorm: one wave per row of 512; writes fp16
// ---------------------------------------------------------------------------
__global__ __launch_bounds__(256)
void ln_k(const float* __restrict__ x, f16* __restrict__ oh,
          const float* __restrict__ sc, const float* __restrict__ bi)
{
    const int  lane = threadIdx.x & 63;
    const long row  = (long)blockIdx.x * 4 + (threadIdx.x >> 6);
    const float* p = x + row * 512 + lane * 8;
    float v[8];
    *(float4*)&v[0] = *(const float4*)p;
    *(float4*)&v[4] = *(const float4*)(p + 4);
    float s = 0.f;
#pragma unroll
    for (int j = 0; j < 8; ++j) s += v[j];
#pragma unroll
    for (int m = 1; m < 64; m <<= 1) s += __shfl_xor(s, m, 64);
    const float mu = s * (1.f / 512.f);
    float q = 0.f;
#pragma unroll
    for (int j = 0; j < 8; ++j) { float d = v[j] - mu; q += d * d; }
#pragma unroll
    for (int m = 1; m < 64; m <<= 1) q += __shfl_xor(q, m, 64);
    const float rs = rsqrtf(q * (1.f / 512.f) + 1e-5f);
    float sv[8], bv[8];
    *(float4*)&sv[0] = *(const float4*)(sc + lane * 8);
    *(float4*)&sv[4] = *(const float4*)(sc + lane * 8 + 4);
    *(float4*)&bv[0] = *(const float4*)(bi + lane * 8);
    *(float4*)&bv[4] = *(const float4*)(bi + lane * 8 + 4);
    f16x8 vh;
#pragma unroll
    for (int j = 0; j < 8; ++j)
        vh[j] = (f16)((v[j] - mu) * rs * sv[j] + bv[j]);
    *(f16x8*)(oh + row * 512 + lane * 8) = vh;
}

// ---------------------------------------------------------------------------
// Chunked linear recurrence (complex, fp32 state). Bu: (Mg x 256) fp16.
// ---------------------------------------------------------------------------
__global__ __launch_bounds__(256)
void scan_local_k(const f16* __restrict__ Bu, float* __restrict__ fin,
                  const float* __restrict__ lre, const float* __restrict__ lim, int nB)
{
    const int g = blockIdx.x * 256 + threadIdx.x;
    const int p = g & 127;
    const int c = (g >> 7) & 63;
    const int b = g >> 13;
    if (b >= nB) return;
    const float ar = lre[p], ai = lim[p];
    const f16* base = Bu + ((long)(b * Ll + c * 64)) * 256 + p;
    float xr = 0.f, xi = 0.f;
#pragma unroll 4
    for (int j = 0; j < 64; ++j) {
        float br  = (float)base[j * 256];
        float bi2 = (float)base[j * 256 + 128];
        float nr = fmaf(ar, xr, fmaf(-ai, xi, br));
        float ni = fmaf(ar, xi, fmaf( ai, xr, bi2));
        xr = nr; xi = ni;
    }
    long o = ((long)(b * 64 + c)) * 256 + p;
    fin[o] = xr; fin[o + 128] = xi;
}

// wave-parallel carry scan: one wave per (b, p); lane = chunk index
__global__ __launch_bounds__(256)
void scan_carry_k(const float* __restrict__ fin, float* __restrict__ carry,
                  const float* __restrict__ pre, const float* __restrict__ pim, int nB)
{
    const int wv   = blockIdx.x * 4 + (threadIdx.x >> 6);
    const int lane = threadIdx.x & 63;          // chunk c
    if (wv >= nB * 128) return;
    const int b = wv >> 7;
    const int p = wv & 127;
    const long o = ((long)(b * 64 + lane)) * 256 + p;
    float xr = fin[o], xi = fin[o + 128];
    float ar = pre[p], ai = pim[p];             // lam_bar^64
#pragma unroll
    for (int s = 1; s < 64; s <<= 1) {
        float par = __shfl_up(ar, s, 64);
        float pai = __shfl_up(ai, s, 64);
        float pxr = __shfl_up(xr, s, 64);
        float pxi = __shfl_up(xi, s, 64);
        if (lane >= s) {
            float nxr = fmaf(ar, pxr, fmaf(-ai, pxi, xr));
            float nxi = fmaf(ar, pxi, fmaf( ai, pxr, xi));
            float nar = ar * par - ai * pai;
            float nai = ar * pai + ai * par;
            xr = nxr; xi = nxi; ar = nar; ai = nai;
        }
    }
    float cr = __shfl_up(xr, 1, 64);            // exclusive
    float ci = __shfl_up(xi, 1, 64);
    if (lane == 0) { cr = 0.f; ci = 0.f; }
    carry[o] = cr; carry[o + 128] = ci;
}

// replay with carry; writes xs as fp16 (GEMM A operand)
__global__ __launch_bounds__(256)
void scan_final_k(const f16* __restrict__ Bu, const float* __restrict__ carry,
                  f16* __restrict__ xh,
                  const float* __restrict__ lre, const float* __restrict__ lim, int nB)
{
    const int g = blockIdx.x * 256 + threadIdx.x;
    const int p = g & 127;
    const int c = (g >> 7) & 63;
    const int b = g >> 13;
    if (b >= nB) return;
    const float ar = lre[p], ai = lim[p];
    long co = ((long)(b * 64 + c)) * 256 + p;
    float xr = carry[co], xi = carry[co + 128];
    const f16* base = Bu + ((long)(b * Ll + c * 64)) * 256 + p;
    f16* bh = xh + ((long)(b * Ll + c * 64)) * 256 + p;
#pragma unroll 4
    for (int j = 0; j < 64; ++j) {
        float br  = (float)base[j * 256];
        float bi2 = (float)base[j * 256 + 128];
        float nr = fmaf(ar, xr, fmaf(-ai, xi, br));
        float ni = fmaf(ar, xi, fmaf( ai, xr, bi2));
        xr = nr; xi = ni;
        bh[j * 256]       = (f16)xr;
        bh[j * 256 + 128] = (f16)xi;
    }
}

// ---------------------------------------------------------------------------
// fp16 MFMA GEMM, OPERAND-SWAPPED so each lane owns 4 consecutive n:
//   acc[i][j] = mfma(bf[j], af[i], acc)  =>  D[n][m], lane: m = l15,
//   n = l4*4 + r  -> vectorized float4 / f16x4 epilogues.
// BM=128, BN in {128,64}, BK=32, 256 thr = 4 waves.
// AF32: A operand is fp32 (converted during staging).
// EPI: 0 outq=(f16)v | 1 C=v+bias | 2 outq=(f16)gelu(v+aux*bias)
//    | 3 C += aux*sigmoid(v+bias) | 4 EPI3 + outq=(f16)C_new
// ---------------------------------------------------------------------------
template<int BN, int EPI, bool AF32>
__global__ __launch_bounds__(256)
void mgemm_k(const void* __restrict__ Ap, const f16* __restrict__ Bw,
             float* __restrict__ C, int N, int Kd,
             const float* __restrict__ bias,
             const f16* __restrict__ aux, f16* __restrict__ outq)
{
    constexpr int BM = 128, BK = 32, LDA = 40;
    constexpr int FM = (BN == 128) ? 4 : 2;
    constexpr int WM = FM * 16;            // 64 or 32
    constexpr int FN = 4;                  // WN = 64
    __shared__ __align__(16) f16 As[BM][LDA];
    __shared__ __align__(16) f16 Bs[BN][LDA];

    const f16*   A16 = (const f16*)Ap;
    const float* A32 = (const float*)Ap;

    const int tid  = threadIdx.x;
    const int wid  = tid >> 6;
    const int lane = tid & 63;
    const int l15  = lane & 15;
    const int l4   = lane >> 4;
    const int wm   = (BN == 128) ? (wid >> 1) : wid;
    const int wn   = (BN == 128) ? (wid & 1) : 0;

    const long bm = (long)blockIdx.y * BM;
    const int  bn = blockIdx.x * BN;

    f32x4 acc[FM][FN];
#pragma unroll
    for (int i = 0; i < FM; ++i)
#pragma unroll
        for (int j = 0; j < FN; ++j) acc[i][j] = (f32x4){0.f, 0.f, 0.f, 0.f};

    const int arow = tid >> 1;
    const int akc  = (tid & 1) * 16;
    const int brow = (BN == 128) ? (tid >> 1) : (tid >> 2);
    const int bko  = (BN == 128) ? ((tid & 1) * 16) : ((tid & 3) * 8);
    constexpr int NBL = (BN == 128) ? 2 : 1;

    f16x8 ra[2], rb[2];
    auto LOADT = [&](int k0) {
        if constexpr (AF32) {
            const float* ap = A32 + (bm + arow) * (long)Kd + k0 + akc;
            float4 t0 = ((const float4*)ap)[0];
            float4 t1 = ((const float4*)ap)[1];
            float4 t2 = ((const float4*)ap)[2];
            float4 t3 = ((const float4*)ap)[3];
            ra[0] = (f16x8){(f16)t0.x,(f16)t0.y,(f16)t0.z,(f16)t0.w,
                            (f16)t1.x,(f16)t1.y,(f16)t1.z,(f16)t1.w};
            ra[1] = (f16x8){(f16)t2.x,(f16)t2.y,(f16)t2.z,(f16)t2.w,
                            (f16)t3.x,(f16)t3.y,(f16)t3.z,(f16)t3.w};
        } else {
            const long aoff = (bm + arow) * (long)Kd + k0 + akc;
            ra[0] = *(const f16x8*)(A16 + aoff);
            ra[1] = *(const f16x8*)(A16 + aoff + 8);
        }
        const long boff = (long)(bn + brow) * Kd + k0 + bko;
        rb[0] = *(const f16x8*)(Bw + boff);
        if constexpr (NBL == 2) rb[1] = *(const f16x8*)(Bw + boff + 8);
    };

    LOADT(0);
    for (int k0 = 0; k0 < Kd; k0 += BK) {
        __syncthreads();
        *(f16x8*)&As[arow][akc]     = ra[0];
        *(f16x8*)&As[arow][akc + 8] = ra[1];
        *(f16x8*)&Bs[brow][bko] = rb[0];
        if constexpr (NBL == 2) *(f16x8*)&Bs[brow][bko + 8] = rb[1];
        __syncthreads();
        if (k0 + BK < Kd) LOADT(k0 + BK);    // prefetch next tile over MFMA phase

        f16x8 bf[FN];
#pragma unroll
        for (int j = 0; j < FN; ++j)
            bf[j] = *(const f16x8*)&Bs[wn * 64 + j * 16 + l15][l4 * 8];
#pragma unroll
        for (int i = 0; i < FM; ++i) {
            f16x8 af = *(const f16x8*)&As[wm * WM + i * 16 + l15][l4 * 8];
#pragma unroll
            for (int j = 0; j < FN; ++j)   // swapped operands: D[n][m]
                acc[i][j] = __builtin_amdgcn_mfma_f32_16x16x32_f16(bf[j], af, acc[i][j], 0, 0, 0);
        }
    }

#pragma unroll
    for (int i = 0; i < FM; ++i) {
        const int m = (int)(bm + wm * WM + i * 16 + l15);
#pragma unroll
        for (int j = 0; j < FN; ++j) {
            const int  n0  = bn + wn * 64 + j * 16 + l4 * 4;
            const long off = (long)m * N + n0;
            f32x4 v = acc[i][j];
            if constexpr (EPI == 0) {
                *(f16x4*)(outq + off) = (f16x4){(f16)v[0], (f16)v[1], (f16)v[2], (f16)v[3]};
            } else if constexpr (EPI == 1) {
                const float4 bb = *(const float4*)(bias + n0);
                *(float4*)(C + off) = make_float4(v[0]+bb.x, v[1]+bb.y, v[2]+bb.z, v[3]+bb.w);
            } else if constexpr (EPI == 2) {
                const float4 bb = *(const float4*)(bias + n0);
                const f16x4 uu = *(const f16x4*)(aux + off);
                f16x4 o4;
#pragma unroll
                for (int r = 0; r < 4; ++r) {
                    float bvr = (r == 0 ? bb.x : r == 1 ? bb.y : r == 2 ? bb.z : bb.w);
                    float y = v[r] + (float)uu[r] * bvr;
                    float t = tanhf(0.7978845608028654f * (y + 0.044715f * y * y * y));
                    o4[r] = (f16)(0.5f * y * (1.f + t));
                }
                *(f16x4*)(outq + off) = o4;
            } else {  // EPI 3 or 4
                const float4 bb = *(const float4*)(bias + n0);
                const f16x4 uu = *(const f16x4*)(aux + off);
                float4 hh = *(const float4*)(C + off);
                float z0 = v[0]+bb.x, z1 = v[1]+bb.y, z2 = v[2]+bb.z, z3 = v[3]+bb.w;
                hh.x += (float)uu[0] / (1.f + expf(-z0));
                hh.y += (float)uu[1] / (1.f + expf(-z1));
                hh.z += (float)uu[2] / (1.f + expf(-z2));
                hh.w += (float)uu[3] / (1.f + expf(-z3));
                *(float4*)(C + off) = hh;
                if constexpr (EPI == 4)
                    *(f16x4*)(outq + off) = (f16x4){(f16)hh.x, (f16)hh.y, (f16)hh.z, (f16)hh.w};
            }
        }
    }
}

// ---------------------------------------------------------------------------
// Launch (workspace-adaptive grouping over the 16 independent sequences)
// ---------------------------------------------------------------------------
extern "C" void kernel_launch(void* const* d_in, const int* in_sizes, int n_in,
                              void* d_out, int out_size, void* d_ws, size_t ws_size,
                              hipStream_t stream)
{
    const float* x        = (const float*)d_in[0];
    const float* W_enc    = (const float*)d_in[1];
    const float* b_enc    = (const float*)d_in[2];
    const float* ln_scale = (const float*)d_in[3];
    const float* ln_bias  = (const float*)d_in[4];
    const float* Lre      = (const float*)d_in[5];
    const float* Lim      = (const float*)d_in[6];
    const float* B_re     = (const float*)d_in[7];
    const float* B_im     = (const float*)d_in[8];
    const float* C_re     = (const float*)d_in[9];
    const float* C_im     = (const float*)d_in[10];
    const float* Dv       = (const float*)d_in[11];
    const float* log_step = (const float*)d_in[12];
    const float* W_glu    = (const float*)d_in[13];
    const float* b_glu    = (const float*)d_in[14];
    const float* W_dec    = (const float*)d_in[15];
    const float* b_dec    = (const float*)d_in[16];
    float* out = (float*)d_out;

    char* w = (char*)d_ws;
    auto alloc = [&](size_t nbytes) { char* p = w; w += (nbytes + 255) & ~255ull; return p; };

    float* lam_re = (float*)alloc(768 * 4);
    float* lam_im = (float*)alloc(768 * 4);
    float* pow_re = (float*)alloc(768 * 4);
    float* pow_im = (float*)alloc(768 * 4);
    float* coef_re= (float*)alloc(768 * 4);
    float* coef_im= (float*)alloc(768 * 4);
    float* fin    = (float*)alloc((size_t)Bb * 64 * 256 * 4);
    float* carry  = (float*)alloc((size_t)Bb * 64 * 256 * 4);
    f16* WencH = (f16*)alloc((size_t)Hd * INd * 2);
    f16* WbuH  = (f16*)alloc((size_t)Kn * 256 * Hd * 2);
    f16* WcH   = (f16*)alloc((size_t)Kn * Hd * 256 * 2);
    f16* WgluH = (f16*)alloc((size_t)Kn * Hd * Hd * 2);
    f16* WdecH = (f16*)alloc((size_t)OUTd * Hd * 2);
    const size_t fixed_bytes = (size_t)(w - (char*)d_ws);

    // per-row bytes: h(2048) + uh(1024) + Buh(512) + xsh(512) = 4096
    int G = 1;
    for (; G < 16; G *= 2) {
        size_t Mg = Mrows / G;
        if (fixed_bytes + Mg * 4096ull <= ws_size) break;
    }
    const long Bg = Bb / G;
    const long Mg = Bg * Ll;

    float* h   = (float*)alloc((size_t)Mg * Hd * 4);
    f16*   uh  = (f16*)alloc((size_t)Mg * Hd * 2);   // LN out; g; fp16(h) for decoder
    f16*   Buh = (f16*)alloc((size_t)Mg * 256 * 2);
    f16*   xsh = (f16*)alloc((size_t)Mg * 256 * 2);

    // --- prep ---
    prep_lam_k <<<3,    256, 0, stream>>>(Lre, Lim, log_step, lam_re, lam_im,
                                          pow_re, pow_im, coef_re, coef_im);
    prep_bbar_k<<<1536, 256, 0, stream>>>(B_re, B_im, coef_re, coef_im, WbuH);
    prep_c_k   <<<1536, 256, 0, stream>>>(C_re, C_im, WcH);
    cvt_w_k    <<<6144, 256, 0, stream>>>(W_glu, WgluH, (long)Kn * Hd * Hd);
    cvt_w_k    <<<384,  256, 0, stream>>>(W_enc, WencH, (long)Hd * INd);
    cvt_w_k    <<<384,  256, 0, stream>>>(W_dec, WdecH, (long)OUTd * Hd);

    const dim3 blk(256);
    const int gy = (int)(Mg / 128);
    for (int g0 = 0; g0 < G; ++g0) {
        const float* xg   = x   + (size_t)g0 * Mg * INd;
        float*       outg = out + (size_t)g0 * Mg * OUTd;

        // encoder (fp32 A, cvt in staging): h = x @ Wenc^T + b_enc
        mgemm_k<128, 1, true><<<dim3(4, gy), blk, 0, stream>>>(
            xg, WencH, h, 512, INd, b_enc, nullptr, nullptr);

        for (int k = 0; k < Kn; ++k) {
            ln_k<<<(int)(Mg / 4), 256, 0, stream>>>(h, uh,
                                                    ln_scale + k * 512, ln_bias + k * 512);
            // Bu = u @ Wbu[k]^T (M x 256, K=512), fp16 out
            mgemm_k<128, 0, false><<<dim3(2, gy), blk, 0, stream>>>(
                uh, WbuH + (size_t)k * 256 * Hd, nullptr, 256, 512, nullptr, nullptr, Buh);
            scan_local_k<<<(int)(Bg * 32), 256, 0, stream>>>(
                Buh, fin, lam_re + k * 128, lam_im + k * 128, (int)Bg);
            scan_carry_k<<<(int)(Bg * 32), 256, 0, stream>>>(
                fin, carry, pow_re + k * 128, pow_im + k * 128, (int)Bg);
            scan_final_k<<<(int)(Bg * 32), 256, 0, stream>>>(
                Buh, carry, xsh, lam_re + k * 128, lam_im + k * 128, (int)Bg);
            // g = gelu(xs @ Wc[k]^T + u*D), fp16, in place over u
            mgemm_k<128, 2, false><<<dim3(4, gy), blk, 0, stream>>>(
                xsh, WcH + (size_t)k * Hd * 256, nullptr, 512, 256,
                Dv + k * 512, uh, uh);
            // h += g * sigmoid(g @ Wglu[k]^T + b_glu); last layer also emits fp16(h)
            if (k < Kn - 1)
                mgemm_k<128, 3, false><<<dim3(4, gy), blk, 0, stream>>>(
                    uh, WgluH + (size_t)k * Hd * Hd, h, 512, 512,
                    b_glu + k * 512, uh, nullptr);
            else
                mgemm_k<128, 4, false><<<dim3(4, gy), blk, 0, stream>>>(
                    uh, WgluH + (size_t)k * Hd * Hd, h, 512, 512,
                    b_glu + k * 512, uh, uh);
        }
        // decoder: out = h @ Wdec^T + b_dec
        mgemm_k<64, 1, false><<<dim3(3, gy), blk, 0, stream>>>(
            uh, WdecH, outg, 192, 512, b_dec, nullptr, nullptr);
    }
}